// Round 3
// baseline (216.482 us; speedup 1.0000x reference)
//
#include <hip/hip_runtime.h>

// Problem constants: B=1, N=16, T=2048, E=64, H=4, D=16
#define N_ 16
#define T_ 2048
#define E_ 64
#define H_ 4
#define D_ 16
#define NH_ 64            // N_*H_
#define SEXP_ 0.18033688f // 0.125 * log2(e):  exp(s/8) == exp2(s*SEXP_)

typedef __attribute__((ext_vector_type(4))) _Float16 h4;
typedef __attribute__((ext_vector_type(8))) _Float16 h8;
typedef __attribute__((ext_vector_type(2))) __fp16 g2;
typedef __attribute__((ext_vector_type(4))) float f4;

#if __has_builtin(__builtin_amdgcn_exp2f)
__device__ inline float fast_exp2(float x) { return __builtin_amdgcn_exp2f(x); }
#else
__device__ inline float fast_exp2(float x) {
    float r; asm("v_exp_f32 %0, %1" : "=v"(r) : "v"(x)); return r;
}
#endif

#if __has_builtin(__builtin_amdgcn_rcpf)
__device__ inline float fast_rcp(float x) { return __builtin_amdgcn_rcpf(x); }
#else
__device__ inline float fast_rcp(float x) {
    float r; asm("v_rcp_f32 %0, %1" : "=v"(r) : "v"(x)); return r;
}
#endif

__device__ inline h4 pack4_f16(float a, float b, float c, float d) {
    union { g2 g[2]; h4 h; } u;
    u.g[0] = __builtin_amdgcn_cvt_pkrtz(a, b);
    u.g[1] = __builtin_amdgcn_cvt_pkrtz(c, d);
    return u.h;
}

// ---------------------------------------------------------------------------
// K1: fused projections (y=0 Q pre-scaled, y=1 K, y=2 V-transposed, y=3 Wfc^T)
// ---------------------------------------------------------------------------
__global__ __launch_bounds__(256) void proj_kernel(
    const float* __restrict__ xq, const float* __restrict__ Wq, const float* __restrict__ bq,
    const float* __restrict__ xk, const float* __restrict__ Wk, const float* __restrict__ bk,
    const float* __restrict__ xv, const float* __restrict__ Wv, const float* __restrict__ bv,
    const float* __restrict__ Wfc,
    _Float16* __restrict__ Qh, _Float16* __restrict__ Kh, _Float16* __restrict__ Vt,
    _Float16* __restrict__ Wt)
{
    int tid = threadIdx.x;
    int y = blockIdx.y;
    if (y == 3) {
        if (blockIdx.x < 16) {
            int k = blockIdx.x * 4 + (tid >> 6);
            int e = tid & 63;
            Wt[e * 64 + k] = (_Float16)Wfc[k * 64 + e];
        }
        return;
    }
    const float* x = (y == 0) ? xq : (y == 1) ? xk : xv;
    const float* W = (y == 0) ? Wq : (y == 1) ? Wk : Wv;
    const float* b = (y == 0) ? bq : (y == 1) ? bk : bv;
    const float sc = (y == 0) ? SEXP_ : 1.0f;

    __shared__ float Wl[D_ * D_];
    __shared__ float bl[D_];
    Wl[tid] = W[tid];
    if (tid < D_) bl[tid] = b[tid];
    __syncthreads();

    int r = blockIdx.x * 256 + tid;
    int h, t, n;
    if (y == 2) {          // t fastest: coalesced transposed stores
        t = r & (T_ - 1);
        h = (r >> 11) & (H_ - 1);
        n = r >> 13;
    } else {               // h fastest: coalesced reads
        h = r & (H_ - 1);
        t = (r >> 2) & (T_ - 1);
        n = r >> 13;
    }

    const float4* xp4 = reinterpret_cast<const float4*>(
        x + ((size_t)(n * T_ + t) * E_ + h * D_));
    float xv_[D_];
#pragma unroll
    for (int i = 0; i < 4; i++) {
        float4 v = xp4[i];
        xv_[4*i] = v.x; xv_[4*i+1] = v.y; xv_[4*i+2] = v.z; xv_[4*i+3] = v.w;
    }
    float acc[D_];
#pragma unroll
    for (int i = 0; i < D_; i++) acc[i] = bl[i];
#pragma unroll
    for (int j = 0; j < D_; j++) {
        float xj = xv_[j];
#pragma unroll
        for (int i = 0; i < D_; i++) acc[i] = fmaf(xj, Wl[j * D_ + i], acc[i]);
    }
    if (y == 2) {
        _Float16* vb = Vt + (size_t)(n * H_ + h) * D_ * T_ + t;
#pragma unroll
        for (int d = 0; d < D_; d++) vb[(size_t)d * T_] = (_Float16)acc[d];
    } else {
        _Float16 ob[16];
#pragma unroll
        for (int i = 0; i < D_; i++) ob[i] = (_Float16)(acc[i] * sc);
        _Float16* o = (y == 0) ? Qh : Kh;
        uint4* dst = reinterpret_cast<uint4*>(o + (size_t)((n * H_ + h) * T_ + t) * D_);
        dst[0] = reinterpret_cast<uint4*>(ob)[0];
        dst[1] = reinterpret_cast<uint4*>(ob)[1];
    }
}

// ---------------------------------------------------------------------------
// K2: single-pass fused stats+attn.
//   One block per (nh, z): 16 waves x 8 q-tiles cover ALL 2048 q; k-range =
//   z*512..+512 in 16 chunks of 32 k.  Per chunk:
//     S-phase: permuted-K S-MFMAs -> exp2 ONCE -> E kept in regs (p[8], already
//              in PV A-frag layout thanks to the pr permutation)
//     column sums: f32 lane partials -> shfl_xor over the 16 q-lanes ->
//              32 LDS atomicAdd (4 lanes/wave)
//     one __syncthreads, then rl = rcp(l) folded into V, PV MFMAs on retained p.
//   exp2 count is HALVED vs the old stats+attn pair (268M instead of 537M).
//
//   REGISTER BUDGET (hard-won): hipcc DOUBLES the min-waves launch_bounds arg
//   (treats it as 32-wide warps): effective VGPR cap = 256/n, not 512/n.
//   Evidence: (256,8)->32 VGPR [old session], (1024,4)->64 VGPR [R1/R2, still
//   spilling 90 MB/launch].  (1024,2) yields the 128-VGPR cap under EITHER
//   interpretation (true semantics: min-2-waves=256 budget, but the 16-wave
//   flat workgroup itself forces <=128 for residency; doubled semantics:
//   maps to 4 waves/EU = 128).  Persistent state ~115 regs fits 128.
//   unroll 1 on the chunk loop keeps it there.
// ---------------------------------------------------------------------------
__global__ __launch_bounds__(1024, 2) void fused_attn_kernel(
    const _Float16* __restrict__ Qh, const _Float16* __restrict__ Kh,
    const _Float16* __restrict__ Vt, float* __restrict__ PO)
{
    __shared__ __align__(16) float l[3][32];
    int tid = threadIdx.x;
    int lane = tid & 63, wave = tid >> 6;          // wave 0..15
    int row = lane & 15, quad = lane >> 4;
    int nh = blockIdx.x;
    int z = blockIdx.y;
    int k_lo = z * (T_ / 4);

    if (tid < 96) ((float*)l)[tid] = 0.f;

    const _Float16* Kb = Kh + (size_t)nh * T_ * D_;
    const _Float16* Qb = Qh + (size_t)nh * T_ * D_;
    const _Float16* Vb = Vt + (size_t)nh * D_ * T_ + (size_t)row * T_;

    // Q fragments: 8 q-tiles per wave (loop-invariant over the k sweep)
    h4 b[8];
#pragma unroll
    for (int j = 0; j < 8; j++)
        b[j] = *reinterpret_cast<const h4*>(Qb + ((wave * 8 + j) * 16 + row) * D_ + quad * 4);

    f4 o[8];
#pragma unroll
    for (int j = 0; j < 8; j++) o[j] = (f4){0.f, 0.f, 0.f, 0.f};
    f4 z4 = {0.f, 0.f, 0.f, 0.f};

    int pr = ((row & 12) << 1) | (row & 3);   // permuted K-row offset

    // preload chunk-0 operands
    h4 a0 = *reinterpret_cast<const h4*>(Kb + (k_lo + pr) * D_ + quad * 4);
    h4 a1 = *reinterpret_cast<const h4*>(Kb + (k_lo + pr + 4) * D_ + quad * 4);
    h8 v  = *reinterpret_cast<const h8*>(Vb + k_lo + quad * 8);

    __syncthreads();   // l zero-init visible

    int cur = 0;
#pragma unroll 1
    for (int c = 0; c < 16; c++) {
        int k0 = k_lo + c * 32;
        h8 p[8];
        float lp[8];
#pragma unroll
        for (int t = 0; t < 8; t++) lp[t] = 0.f;

        // ---- S phase: exp2 computed ONCE, E retained in regs (PV A-layout)
#pragma unroll
        for (int j = 0; j < 8; j++) {
            f4 s0 = __builtin_amdgcn_mfma_f32_16x16x16f16(a0, b[j], z4, 0, 0, 0);
            f4 s1 = __builtin_amdgcn_mfma_f32_16x16x16f16(a1, b[j], z4, 0, 0, 0);
            float e0 = fast_exp2(s0[0]), e1 = fast_exp2(s0[1]),
                  e2 = fast_exp2(s0[2]), e3 = fast_exp2(s0[3]);
            float e4 = fast_exp2(s1[0]), e5 = fast_exp2(s1[1]),
                  e6 = fast_exp2(s1[2]), e7 = fast_exp2(s1[3]);
            lp[0] += e0; lp[1] += e1; lp[2] += e2; lp[3] += e3;
            lp[4] += e4; lp[5] += e5; lp[6] += e6; lp[7] += e7;
            union { h4 h[2]; h8 h8v; } pk;
            pk.h[0] = pack4_f16(e0, e1, e2, e3);
            pk.h[1] = pack4_f16(e4, e5, e6, e7);
            p[j] = pk.h8v;
        }

        // prefetch next chunk's K/V (latency hidden under reduce+barrier+PV)
        int kn = (c == 15) ? k_lo : k0 + 32;
        h4 na0 = *reinterpret_cast<const h4*>(Kb + (kn + pr) * D_ + quad * 4);
        h4 na1 = *reinterpret_cast<const h4*>(Kb + (kn + pr + 4) * D_ + quad * 4);
        h8 nv  = *reinterpret_cast<const h8*>(Vb + kn + quad * 8);

        // ---- column sums over q: 16 q-lanes per group, then cross-wave atomics
#pragma unroll
        for (int off = 1; off < 16; off <<= 1)
#pragma unroll
            for (int t = 0; t < 8; t++) lp[t] += __shfl_xor(lp[t], off, 64);
        if (row == 0) {
#pragma unroll
            for (int t = 0; t < 8; t++) atomicAdd(&l[cur][quad * 8 + t], lp[t]);
        }
        __syncthreads();

        // zero the buffer chunk c+2 will use (readers of it finished before
        // this barrier; its next writers are beyond the next barrier)
        int zb = cur + 2; if (zb >= 3) zb -= 3;
        if (wave == 0 && lane < 32) l[zb][lane] = 0.f;

        // ---- rl = 1/l for this lane's 8 k's, fold into V fragment
        f4 la = *reinterpret_cast<f4*>(&l[cur][quad * 8]);
        f4 lb = *reinterpret_cast<f4*>(&l[cur][quad * 8 + 4]);
        union { h4 h[2]; h8 h8v; } rk;
        rk.h[0] = pack4_f16(fast_rcp(la[0]), fast_rcp(la[1]),
                            fast_rcp(la[2]), fast_rcp(la[3]));
        rk.h[1] = pack4_f16(fast_rcp(lb[0]), fast_rcp(lb[1]),
                            fast_rcp(lb[2]), fast_rcp(lb[3]));
        h8 vs = v * rk.h8v;

        // ---- PV on retained E fragments
#pragma unroll
        for (int j = 0; j < 8; j++)
            o[j] = __builtin_amdgcn_mfma_f32_16x16x32_f16(p[j], vs, o[j], 0, 0, 0);

        a0 = na0; a1 = na1; v = nv;
        cur = cur + 1; if (cur >= 3) cur -= 3;
    }

    int n = nh >> 2, h = nh & 3;
    float* po = PO + (size_t)z * N_ * T_ * E_ + (size_t)n * T_ * E_ + h * D_ + row;
#pragma unroll
    for (int j = 0; j < 8; j++)
#pragma unroll
        for (int i = 0; i < 4; i++) {
            int q0 = (wave * 8 + j) * 16 + quad * 4 + i;
            po[(size_t)q0 * E_] = o[j][i];
        }
}

// ---------------------------------------------------------------------------
// K4: fc — out = (sum_z PO[z]) @ Wfc + bfc via 16x16x32 MFMA on Wt.
//     wave: one 16-row M-tile; 2048 tiles -> 512 blocks.
// ---------------------------------------------------------------------------
__global__ __launch_bounds__(256) void fc_kernel(
    const float* __restrict__ PO, const _Float16* __restrict__ Wt,
    const float* __restrict__ bfc, float* __restrict__ out)
{
    int tid = threadIdx.x;
    int lane = tid & 63, wave = tid >> 6;
    int row = lane & 15, quad = lane >> 4;
    int g = blockIdx.x * 4 + wave;             // M-tile id, 2048 total
    int r0 = g * 16;
    size_t base = (size_t)(r0 + row) * E_;
    const size_t zstride = (size_t)N_ * T_ * E_ / 4;   // f4 units

    h8 a[2];
#pragma unroll
    for (int half = 0; half < 2; half++) {
        f4 u0 = {0.f,0.f,0.f,0.f}, u1 = {0.f,0.f,0.f,0.f};
#pragma unroll
        for (int zz = 0; zz < 4; zz++) {
            const f4* p = reinterpret_cast<const f4*>(PO) + zz * zstride + base / 4;
            f4 w0 = p[half * 8 + quad * 2];
            f4 w1 = p[half * 8 + quad * 2 + 1];
#pragma unroll
            for (int i = 0; i < 4; i++) { u0[i] += w0[i]; u1[i] += w1[i]; }
        }
        union { h4 h[2]; h8 v; } pk;
        pk.h[0] = pack4_f16(u0[0], u0[1], u0[2], u0[3]);
        pk.h[1] = pack4_f16(u1[0], u1[1], u1[2], u1[3]);
        a[half] = pk.v;
    }
    f4 acc[4];
#pragma unroll
    for (int ne = 0; ne < 4; ne++) {
        const _Float16* wtb = Wt + (size_t)(ne * 16 + row) * 64;
        h8 b0 = *reinterpret_cast<const h8*>(wtb + quad * 8);
        h8 b1 = *reinterpret_cast<const h8*>(wtb + 32 + quad * 8);
        acc[ne] = __builtin_amdgcn_mfma_f32_16x16x32_f16(a[0], b0, (f4){0.f,0.f,0.f,0.f}, 0, 0, 0);
        acc[ne] = __builtin_amdgcn_mfma_f32_16x16x32_f16(a[1], b1, acc[ne], 0, 0, 0);
    }
#pragma unroll
    for (int ne = 0; ne < 4; ne++) {
        float bias = bfc[ne * 16 + row];
#pragma unroll
        for (int i = 0; i < 4; i++)
            out[(size_t)(r0 + quad * 4 + i) * E_ + ne * 16 + row] = acc[ne][i] + bias;
    }
}

extern "C" void kernel_launch(void* const* d_in, const int* in_sizes, int n_in,
                              void* d_out, int out_size, void* d_ws, size_t ws_size,
                              hipStream_t stream) {
    (void)in_sizes; (void)n_in; (void)out_size; (void)ws_size;
    const float* value = (const float*)d_in[0];
    const float* key   = (const float*)d_in[1];
    const float* query = (const float*)d_in[2];
    const float* Wq    = (const float*)d_in[3];
    const float* bq    = (const float*)d_in[4];
    const float* Wk    = (const float*)d_in[5];
    const float* bk    = (const float*)d_in[6];
    const float* Wv    = (const float*)d_in[7];
    const float* bv    = (const float*)d_in[8];
    const float* Wfc   = (const float*)d_in[9];
    const float* bfc   = (const float*)d_in[10];
    float* out = (float*)d_out;

    // ws bytes: Qh 0-4M | Kh 4-8M | Vt 8-12M | Wt 12M | (13-15M free) | PO 15-47M
    char* ws = (char*)d_ws;
    _Float16* Qh  = (_Float16*)(ws);
    _Float16* Kh  = (_Float16*)(ws + (4u << 20));
    _Float16* Vt  = (_Float16*)(ws + (8u << 20));
    _Float16* Wt  = (_Float16*)(ws + (12u << 20));
    float*    PO  = (float*)   (ws + (15u << 20));

    proj_kernel<<<dim3(512, 4), 256, 0, stream>>>(
        query, Wq, bq, key, Wk, bk, value, Wv, bv, Wfc, Qh, Kh, Vt, Wt);
    fused_attn_kernel<<<dim3(NH_, 4), 1024, 0, stream>>>(Qh, Kh, Vt, PO);
    fc_kernel<<<512, 256, 0, stream>>>(PO, Wt, bfc, out);
}

// Round 4
// 195.796 us; speedup vs baseline: 1.1056x; 1.1056x over previous
//
#include <hip/hip_runtime.h>

// Problem constants: B=1, N=16, T=2048, E=64, H=4, D=16
#define N_ 16
#define T_ 2048
#define E_ 64
#define H_ 4
#define D_ 16
#define NH_ 64            // N_*H_
#define SEXP_ 0.18033688f // 0.125 * log2(e):  exp(s/8) == exp2(s*SEXP_)

typedef __attribute__((ext_vector_type(4))) _Float16 h4;
typedef __attribute__((ext_vector_type(8))) _Float16 h8;
typedef __attribute__((ext_vector_type(2))) __fp16 g2;
typedef __attribute__((ext_vector_type(4))) float f4;

#if __has_builtin(__builtin_amdgcn_exp2f)
__device__ inline float fast_exp2(float x) { return __builtin_amdgcn_exp2f(x); }
#else
__device__ inline float fast_exp2(float x) {
    float r; asm("v_exp_f32 %0, %1" : "=v"(r) : "v"(x)); return r;
}
#endif

#if __has_builtin(__builtin_amdgcn_rcpf)
__device__ inline float fast_rcp(float x) { return __builtin_amdgcn_rcpf(x); }
#else
__device__ inline float fast_rcp(float x) {
    float r; asm("v_rcp_f32 %0, %1" : "=v"(r) : "v"(x)); return r;
}
#endif

__device__ inline h4 pack4_f16(float a, float b, float c, float d) {
    union { g2 g[2]; h4 h; } u;
    u.g[0] = __builtin_amdgcn_cvt_pkrtz(a, b);
    u.g[1] = __builtin_amdgcn_cvt_pkrtz(c, d);
    return u.h;
}

// ---------------------------------------------------------------------------
// K1: fused projections (y=0 Q pre-scaled, y=1 K, y=2 V-transposed, y=3 Wfc^T)
// ---------------------------------------------------------------------------
__global__ __launch_bounds__(256) void proj_kernel(
    const float* __restrict__ xq, const float* __restrict__ Wq, const float* __restrict__ bq,
    const float* __restrict__ xk, const float* __restrict__ Wk, const float* __restrict__ bk,
    const float* __restrict__ xv, const float* __restrict__ Wv, const float* __restrict__ bv,
    const float* __restrict__ Wfc,
    _Float16* __restrict__ Qh, _Float16* __restrict__ Kh, _Float16* __restrict__ Vt,
    _Float16* __restrict__ Wt)
{
    int tid = threadIdx.x;
    int y = blockIdx.y;
    if (y == 3) {
        if (blockIdx.x < 16) {
            int k = blockIdx.x * 4 + (tid >> 6);
            int e = tid & 63;
            Wt[e * 64 + k] = (_Float16)Wfc[k * 64 + e];
        }
        return;
    }
    const float* x = (y == 0) ? xq : (y == 1) ? xk : xv;
    const float* W = (y == 0) ? Wq : (y == 1) ? Wk : Wv;
    const float* b = (y == 0) ? bq : (y == 1) ? bk : bv;
    const float sc = (y == 0) ? SEXP_ : 1.0f;

    __shared__ float Wl[D_ * D_];
    __shared__ float bl[D_];
    Wl[tid] = W[tid];
    if (tid < D_) bl[tid] = b[tid];
    __syncthreads();

    int r = blockIdx.x * 256 + tid;
    int h, t, n;
    if (y == 2) {          // t fastest: coalesced transposed stores
        t = r & (T_ - 1);
        h = (r >> 11) & (H_ - 1);
        n = r >> 13;
    } else {               // h fastest: coalesced reads
        h = r & (H_ - 1);
        t = (r >> 2) & (T_ - 1);
        n = r >> 13;
    }

    const float4* xp4 = reinterpret_cast<const float4*>(
        x + ((size_t)(n * T_ + t) * E_ + h * D_));
    float xv_[D_];
#pragma unroll
    for (int i = 0; i < 4; i++) {
        float4 v = xp4[i];
        xv_[4*i] = v.x; xv_[4*i+1] = v.y; xv_[4*i+2] = v.z; xv_[4*i+3] = v.w;
    }
    float acc[D_];
#pragma unroll
    for (int i = 0; i < D_; i++) acc[i] = bl[i];
#pragma unroll
    for (int j = 0; j < D_; j++) {
        float xj = xv_[j];
#pragma unroll
        for (int i = 0; i < D_; i++) acc[i] = fmaf(xj, Wl[j * D_ + i], acc[i]);
    }
    if (y == 2) {
        _Float16* vb = Vt + (size_t)(n * H_ + h) * D_ * T_ + t;
#pragma unroll
        for (int d = 0; d < D_; d++) vb[(size_t)d * T_] = (_Float16)acc[d];
    } else {
        _Float16 ob[16];
#pragma unroll
        for (int i = 0; i < D_; i++) ob[i] = (_Float16)(acc[i] * sc);
        _Float16* o = (y == 0) ? Qh : Kh;
        uint4* dst = reinterpret_cast<uint4*>(o + (size_t)((n * H_ + h) * T_ + t) * D_);
        dst[0] = reinterpret_cast<uint4*>(ob)[0];
        dst[1] = reinterpret_cast<uint4*>(ob)[1];
    }
}

// ---------------------------------------------------------------------------
// K2: single-pass fused stats+attn.
//   One block per (nh, z): 16 waves x 8 q-tiles cover ALL 2048 q; k-range =
//   z*512..+512 in 16 chunks of 32 k.  Per chunk:
//     S-phase: permuted-K S-MFMAs -> exp2 ONCE -> E kept in regs (p[8], already
//              in PV A-frag layout thanks to the pr permutation)
//     column sums: f32 lane partials -> shfl_xor over the 16 q-lanes ->
//              32 LDS atomicAdd (4 lanes/wave)
//     one __syncthreads, then rl = rcp(l) folded into V, PV MFMAs on retained p.
//   exp2 count is HALVED vs the old stats+attn pair (268M instead of 537M).
//
//   REGISTER BUDGET (3 rounds of evidence): __launch_bounds__'s 2nd arg is a
//   MINIMUM waves/EU — the allocator takes max(min, heuristic), and with tiny
//   LDS the heuristic picks 8 waves/EU -> 64-VGPR cap -> ~90 MB/launch of
//   scratch spills (R1-R3: (1024,4) and (1024,2) both measured VGPR=64,
//   WRITE_SIZE 124-180 MB vs 34 MB real, 120-126 us).  The MAX is only
//   settable via the raw attribute: amdgpu_waves_per_eu(4,4) pins 4 waves/EU
//   -> 128-VGPR budget.  Persistent state ~110 regs fits.  V-fragment load
//   moved in-loop (consumed only after the barrier -> latency hidden) so only
//   the K-fragment prefetch (4 regs) stays live across the reduce.
// ---------------------------------------------------------------------------
__global__ __attribute__((amdgpu_flat_work_group_size(1024, 1024)))
           __attribute__((amdgpu_waves_per_eu(4, 4)))
void fused_attn_kernel(
    const _Float16* __restrict__ Qh, const _Float16* __restrict__ Kh,
    const _Float16* __restrict__ Vt, float* __restrict__ PO)
{
    __shared__ __align__(16) float l[3][32];
    int tid = threadIdx.x;
    int lane = tid & 63, wave = tid >> 6;          // wave 0..15
    int row = lane & 15, quad = lane >> 4;
    int nh = blockIdx.x;
    int z = blockIdx.y;
    int k_lo = z * (T_ / 4);

    if (tid < 96) ((float*)l)[tid] = 0.f;

    const _Float16* Kb = Kh + (size_t)nh * T_ * D_;
    const _Float16* Qb = Qh + (size_t)nh * T_ * D_;
    const _Float16* Vb = Vt + (size_t)nh * D_ * T_ + (size_t)row * T_;

    // Q fragments: 8 q-tiles per wave (loop-invariant over the k sweep)
    h4 b[8];
#pragma unroll
    for (int j = 0; j < 8; j++)
        b[j] = *reinterpret_cast<const h4*>(Qb + ((wave * 8 + j) * 16 + row) * D_ + quad * 4);

    f4 o[8];
#pragma unroll
    for (int j = 0; j < 8; j++) o[j] = (f4){0.f, 0.f, 0.f, 0.f};
    f4 z4 = {0.f, 0.f, 0.f, 0.f};

    int pr = ((row & 12) << 1) | (row & 3);   // permuted K-row offset

    // preload chunk-0 K fragments
    h4 a0 = *reinterpret_cast<const h4*>(Kb + (k_lo + pr) * D_ + quad * 4);
    h4 a1 = *reinterpret_cast<const h4*>(Kb + (k_lo + pr + 4) * D_ + quad * 4);

    __syncthreads();   // l zero-init visible

    int cur = 0;
#pragma unroll 1
    for (int c = 0; c < 16; c++) {
        int k0 = k_lo + c * 32;
        // V fragment for THIS chunk: consumed only after the barrier below,
        // so the whole S-phase + reduce hides its latency.
        h8 v = *reinterpret_cast<const h8*>(Vb + k0 + quad * 8);

        h8 p[8];
        float lp[8];
#pragma unroll
        for (int t = 0; t < 8; t++) lp[t] = 0.f;

        // ---- S phase: exp2 computed ONCE, E retained in regs (PV A-layout)
#pragma unroll
        for (int j = 0; j < 8; j++) {
            f4 s0 = __builtin_amdgcn_mfma_f32_16x16x16f16(a0, b[j], z4, 0, 0, 0);
            f4 s1 = __builtin_amdgcn_mfma_f32_16x16x16f16(a1, b[j], z4, 0, 0, 0);
            float e0 = fast_exp2(s0[0]), e1 = fast_exp2(s0[1]),
                  e2 = fast_exp2(s0[2]), e3 = fast_exp2(s0[3]);
            float e4 = fast_exp2(s1[0]), e5 = fast_exp2(s1[1]),
                  e6 = fast_exp2(s1[2]), e7 = fast_exp2(s1[3]);
            lp[0] += e0; lp[1] += e1; lp[2] += e2; lp[3] += e3;
            lp[4] += e4; lp[5] += e5; lp[6] += e6; lp[7] += e7;
            union { h4 h[2]; h8 h8v; } pk;
            pk.h[0] = pack4_f16(e0, e1, e2, e3);
            pk.h[1] = pack4_f16(e4, e5, e6, e7);
            p[j] = pk.h8v;
        }

        // prefetch next chunk's K fragments (needed right after next barrier)
        int kn = (c == 15) ? k_lo : k0 + 32;
        h4 na0 = *reinterpret_cast<const h4*>(Kb + (kn + pr) * D_ + quad * 4);
        h4 na1 = *reinterpret_cast<const h4*>(Kb + (kn + pr + 4) * D_ + quad * 4);

        // ---- column sums over q: 16 q-lanes per group, then cross-wave atomics
#pragma unroll
        for (int off = 1; off < 16; off <<= 1)
#pragma unroll
            for (int t = 0; t < 8; t++) lp[t] += __shfl_xor(lp[t], off, 64);
        if (row == 0) {
#pragma unroll
            for (int t = 0; t < 8; t++) atomicAdd(&l[cur][quad * 8 + t], lp[t]);
        }
        __syncthreads();

        // zero the buffer chunk c+2 will use (readers of it finished before
        // this barrier; its next writers are beyond the next barrier)
        int zb = cur + 2; if (zb >= 3) zb -= 3;
        if (wave == 0 && lane < 32) l[zb][lane] = 0.f;

        // ---- rl = 1/l for this lane's 8 k's, fold into V fragment
        f4 la = *reinterpret_cast<f4*>(&l[cur][quad * 8]);
        f4 lb = *reinterpret_cast<f4*>(&l[cur][quad * 8 + 4]);
        union { h4 h[2]; h8 h8v; } rk;
        rk.h[0] = pack4_f16(fast_rcp(la[0]), fast_rcp(la[1]),
                            fast_rcp(la[2]), fast_rcp(la[3]));
        rk.h[1] = pack4_f16(fast_rcp(lb[0]), fast_rcp(lb[1]),
                            fast_rcp(lb[2]), fast_rcp(lb[3]));
        h8 vs = v * rk.h8v;

        // ---- PV on retained E fragments
#pragma unroll
        for (int j = 0; j < 8; j++)
            o[j] = __builtin_amdgcn_mfma_f32_16x16x32_f16(p[j], vs, o[j], 0, 0, 0);

        a0 = na0; a1 = na1;
        cur = cur + 1; if (cur >= 3) cur -= 3;
    }

    int n = nh >> 2, h = nh & 3;
    float* po = PO + (size_t)z * N_ * T_ * E_ + (size_t)n * T_ * E_ + h * D_ + row;
#pragma unroll
    for (int j = 0; j < 8; j++)
#pragma unroll
        for (int i = 0; i < 4; i++) {
            int q0 = (wave * 8 + j) * 16 + quad * 4 + i;
            po[(size_t)q0 * E_] = o[j][i];
        }
}

// ---------------------------------------------------------------------------
// K4: fc — out = (sum_z PO[z]) @ Wfc + bfc via 16x16x32 MFMA on Wt.
//     wave: one 16-row M-tile; 2048 tiles -> 512 blocks.
// ---------------------------------------------------------------------------
__global__ __launch_bounds__(256) void fc_kernel(
    const float* __restrict__ PO, const _Float16* __restrict__ Wt,
    const float* __restrict__ bfc, float* __restrict__ out)
{
    int tid = threadIdx.x;
    int lane = tid & 63, wave = tid >> 6;
    int row = lane & 15, quad = lane >> 4;
    int g = blockIdx.x * 4 + wave;             // M-tile id, 2048 total
    int r0 = g * 16;
    size_t base = (size_t)(r0 + row) * E_;
    const size_t zstride = (size_t)N_ * T_ * E_ / 4;   // f4 units

    h8 a[2];
#pragma unroll
    for (int half = 0; half < 2; half++) {
        f4 u0 = {0.f,0.f,0.f,0.f}, u1 = {0.f,0.f,0.f,0.f};
#pragma unroll
        for (int zz = 0; zz < 4; zz++) {
            const f4* p = reinterpret_cast<const f4*>(PO) + zz * zstride + base / 4;
            f4 w0 = p[half * 8 + quad * 2];
            f4 w1 = p[half * 8 + quad * 2 + 1];
#pragma unroll
            for (int i = 0; i < 4; i++) { u0[i] += w0[i]; u1[i] += w1[i]; }
        }
        union { h4 h[2]; h8 v; } pk;
        pk.h[0] = pack4_f16(u0[0], u0[1], u0[2], u0[3]);
        pk.h[1] = pack4_f16(u1[0], u1[1], u1[2], u1[3]);
        a[half] = pk.v;
    }
    f4 acc[4];
#pragma unroll
    for (int ne = 0; ne < 4; ne++) {
        const _Float16* wtb = Wt + (size_t)(ne * 16 + row) * 64;
        h8 b0 = *reinterpret_cast<const h8*>(wtb + quad * 8);
        h8 b1 = *reinterpret_cast<const h8*>(wtb + 32 + quad * 8);
        acc[ne] = __builtin_amdgcn_mfma_f32_16x16x32_f16(a[0], b0, (f4){0.f,0.f,0.f,0.f}, 0, 0, 0);
        acc[ne] = __builtin_amdgcn_mfma_f32_16x16x32_f16(a[1], b1, acc[ne], 0, 0, 0);
    }
#pragma unroll
    for (int ne = 0; ne < 4; ne++) {
        float bias = bfc[ne * 16 + row];
#pragma unroll
        for (int i = 0; i < 4; i++)
            out[(size_t)(r0 + quad * 4 + i) * E_ + ne * 16 + row] = acc[ne][i] + bias;
    }
}

extern "C" void kernel_launch(void* const* d_in, const int* in_sizes, int n_in,
                              void* d_out, int out_size, void* d_ws, size_t ws_size,
                              hipStream_t stream) {
    (void)in_sizes; (void)n_in; (void)out_size; (void)ws_size;
    const float* value = (const float*)d_in[0];
    const float* key   = (const float*)d_in[1];
    const float* query = (const float*)d_in[2];
    const float* Wq    = (const float*)d_in[3];
    const float* bq    = (const float*)d_in[4];
    const float* Wk    = (const float*)d_in[5];
    const float* bk    = (const float*)d_in[6];
    const float* Wv    = (const float*)d_in[7];
    const float* bv    = (const float*)d_in[8];
    const float* Wfc   = (const float*)d_in[9];
    const float* bfc   = (const float*)d_in[10];
    float* out = (float*)d_out;

    // ws bytes: Qh 0-4M | Kh 4-8M | Vt 8-12M | Wt 12M | (13-15M free) | PO 15-47M
    char* ws = (char*)d_ws;
    _Float16* Qh  = (_Float16*)(ws);
    _Float16* Kh  = (_Float16*)(ws + (4u << 20));
    _Float16* Vt  = (_Float16*)(ws + (8u << 20));
    _Float16* Wt  = (_Float16*)(ws + (12u << 20));
    float*    PO  = (float*)   (ws + (15u << 20));

    proj_kernel<<<dim3(512, 4), 256, 0, stream>>>(
        query, Wq, bq, key, Wk, bk, value, Wv, bv, Wfc, Qh, Kh, Vt, Wt);
    fused_attn_kernel<<<dim3(NH_, 4), 1024, 0, stream>>>(Qh, Kh, Vt, PO);
    fc_kernel<<<512, 256, 0, stream>>>(PO, Wt, bfc, out);
}

// Round 5
// 162.647 us; speedup vs baseline: 1.3310x; 1.2038x over previous
//
#include <hip/hip_runtime.h>

// Problem constants: B=1, N=16, T=2048, E=64, H=4, D=16
#define N_ 16
#define T_ 2048
#define E_ 64
#define H_ 4
#define D_ 16
#define NH_ 64            // N_*H_
#define SEXP_ 0.18033688f // 0.125 * log2(e):  exp(s/8) == exp2(s*SEXP_)

typedef __attribute__((ext_vector_type(4))) _Float16 h4;
typedef __attribute__((ext_vector_type(8))) _Float16 h8;
typedef __attribute__((ext_vector_type(2))) __fp16 g2;
typedef __attribute__((ext_vector_type(4))) float f4;

#if __has_builtin(__builtin_amdgcn_exp2f)
__device__ inline float fast_exp2(float x) { return __builtin_amdgcn_exp2f(x); }
#else
__device__ inline float fast_exp2(float x) {
    float r; asm("v_exp_f32 %0, %1" : "=v"(r) : "v"(x)); return r;
}
#endif

#if __has_builtin(__builtin_amdgcn_rcpf)
__device__ inline float fast_rcp(float x) { return __builtin_amdgcn_rcpf(x); }
#else
__device__ inline float fast_rcp(float x) {
    float r; asm("v_rcp_f32 %0, %1" : "=v"(r) : "v"(x)); return r;
}
#endif

__device__ inline h4 pack4_f16(float a, float b, float c, float d) {
    union { g2 g[2]; h4 h; } u;
    u.g[0] = __builtin_amdgcn_cvt_pkrtz(a, b);
    u.g[1] = __builtin_amdgcn_cvt_pkrtz(c, d);
    return u.h;
}

// ---------------------------------------------------------------------------
// K1: fused projections (y=0 Q pre-scaled, y=1 K, y=2 V-transposed, y=3 Wfc^T)
// ---------------------------------------------------------------------------
__global__ __launch_bounds__(256) void proj_kernel(
    const float* __restrict__ xq, const float* __restrict__ Wq, const float* __restrict__ bq,
    const float* __restrict__ xk, const float* __restrict__ Wk, const float* __restrict__ bk,
    const float* __restrict__ xv, const float* __restrict__ Wv, const float* __restrict__ bv,
    const float* __restrict__ Wfc,
    _Float16* __restrict__ Qh, _Float16* __restrict__ Kh, _Float16* __restrict__ Vt,
    _Float16* __restrict__ Wt)
{
    int tid = threadIdx.x;
    int y = blockIdx.y;
    if (y == 3) {
        if (blockIdx.x < 16) {
            int k = blockIdx.x * 4 + (tid >> 6);
            int e = tid & 63;
            Wt[e * 64 + k] = (_Float16)Wfc[k * 64 + e];
        }
        return;
    }
    const float* x = (y == 0) ? xq : (y == 1) ? xk : xv;
    const float* W = (y == 0) ? Wq : (y == 1) ? Wk : Wv;
    const float* b = (y == 0) ? bq : (y == 1) ? bk : bv;
    const float sc = (y == 0) ? SEXP_ : 1.0f;

    __shared__ float Wl[D_ * D_];
    __shared__ float bl[D_];
    Wl[tid] = W[tid];
    if (tid < D_) bl[tid] = b[tid];
    __syncthreads();

    int r = blockIdx.x * 256 + tid;
    int h, t, n;
    if (y == 2) {          // t fastest: coalesced transposed stores
        t = r & (T_ - 1);
        h = (r >> 11) & (H_ - 1);
        n = r >> 13;
    } else {               // h fastest: coalesced reads
        h = r & (H_ - 1);
        t = (r >> 2) & (T_ - 1);
        n = r >> 13;
    }

    const float4* xp4 = reinterpret_cast<const float4*>(
        x + ((size_t)(n * T_ + t) * E_ + h * D_));
    float xv_[D_];
#pragma unroll
    for (int i = 0; i < 4; i++) {
        float4 v = xp4[i];
        xv_[4*i] = v.x; xv_[4*i+1] = v.y; xv_[4*i+2] = v.z; xv_[4*i+3] = v.w;
    }
    float acc[D_];
#pragma unroll
    for (int i = 0; i < D_; i++) acc[i] = bl[i];
#pragma unroll
    for (int j = 0; j < D_; j++) {
        float xj = xv_[j];
#pragma unroll
        for (int i = 0; i < D_; i++) acc[i] = fmaf(xj, Wl[j * D_ + i], acc[i]);
    }
    if (y == 2) {
        _Float16* vb = Vt + (size_t)(n * H_ + h) * D_ * T_ + t;
#pragma unroll
        for (int d = 0; d < D_; d++) vb[(size_t)d * T_] = (_Float16)acc[d];
    } else {
        _Float16 ob[16];
#pragma unroll
        for (int i = 0; i < D_; i++) ob[i] = (_Float16)(acc[i] * sc);
        _Float16* o = (y == 0) ? Qh : Kh;
        uint4* dst = reinterpret_cast<uint4*>(o + (size_t)((n * H_ + h) * T_ + t) * D_);
        dst[0] = reinterpret_cast<uint4*>(ob)[0];
        dst[1] = reinterpret_cast<uint4*>(ob)[1];
    }
}

// ---------------------------------------------------------------------------
// K2: single-pass fused stats+attn, v3 (k-chunk = 16, register-diet).
//   One block per (nh, z): 16 waves x 8 q-tiles cover ALL 2048 q; k-range =
//   z*512..+512 in 32 chunks of 16 k.  Per chunk:
//     S-phase: 16x16x16 S-MFMAs -> exp2 ONCE -> E kept as h4 p[8] (the 16x16x16
//              D-layout k=quad*4+i ALREADY matches the 16x16x16 PV A-frag, so
//              the old pr permutation is unnecessary)
//     column sums: f4 lane partials -> 4-step shfl_xor over the 16 q-lanes ->
//              16 LDS atomicAdd (4 lanes/wave)
//     one __syncthreads, rl = rcp(l) folded into V (h4), PV MFMAs on p.
//
//   REGISTER BUDGET (4 rounds of evidence): at waves_per_eu(4,4) the unified
//   file splits 64 arch VGPR + 64 AGPR (R4: VGPR_Count=64, SGPR 112, residual
//   ~28 MB spill because arch demand was ~90).  This version is designed to
//   fit 64 ARCH regs outright: p 32->16 (h4), lp 8->4, v 4->2, b[0..3] staged
//   in LDS (32 KB, conflict-free ds_read_b64) leaving only b2[4]=8 persistent;
//   o[8]=32 goes to AGPRs.  Arch ~54 <= 64 -> zero spills under either split
//   model.  Spill tell: WRITE_SIZE > 45 MB means scratch is back.
// ---------------------------------------------------------------------------
__global__ __attribute__((amdgpu_flat_work_group_size(1024, 1024)))
           __attribute__((amdgpu_waves_per_eu(4, 4)))
void fused_attn_kernel(
    const _Float16* __restrict__ Qh, const _Float16* __restrict__ Kh,
    const _Float16* __restrict__ Vt, float* __restrict__ PO)
{
    __shared__ __align__(16) _Float16 Qs[16 * 64 * 16];   // 32 KB: per-wave j<4 tiles
    __shared__ __align__(16) float l[3][16];
    int tid = threadIdx.x;
    int lane = tid & 63, wave = tid >> 6;          // wave 0..15
    int row = lane & 15, quad = lane >> 4;
    int nh = blockIdx.x;
    int z = blockIdx.y;
    int k_lo = z * (T_ / 4);

    const _Float16* Kb = Kh + (size_t)nh * T_ * D_;
    const _Float16* Qb = Qh + (size_t)nh * T_ * D_;
    const _Float16* Vb = Vt + (size_t)nh * D_ * T_ + (size_t)row * T_;

    if (tid < 48) ((float*)l)[tid] = 0.f;

    // stage each wave's first 4 q-tiles (64 rows x 16) into LDS: 32 KB total.
    // LDS layout [w][row64][16] halfs; flat uint4 index u = w*128 + jrow*2 + half.
    {
        const uint4* src = reinterpret_cast<const uint4*>(Qb);
        uint4* dst = reinterpret_cast<uint4*>(Qs);
#pragma unroll
        for (int s = 0; s < 2; s++) {
            int u = tid * 2 + s;
            int w = u >> 7, rem = u & 127;
            int jrow = rem >> 1, half = rem & 1;
            dst[u] = src[(w * 128 + jrow) * 2 + half];
        }
    }

    // persistent Q fragments for j=4..7 only (8 VGPRs)
    h4 b2[4];
#pragma unroll
    for (int j = 0; j < 4; j++)
        b2[j] = *reinterpret_cast<const h4*>(Qb + ((wave * 8 + 4 + j) * 16 + row) * D_ + quad * 4);

    f4 o[8];
#pragma unroll
    for (int j = 0; j < 8; j++) o[j] = (f4){0.f, 0.f, 0.f, 0.f};
    f4 z4 = {0.f, 0.f, 0.f, 0.f};

    // chunk-0 K fragment prefetch (no permutation needed at k-chunk=16)
    h4 a = *reinterpret_cast<const h4*>(Kb + (k_lo + row) * D_ + quad * 4);

    __syncthreads();   // l zero-init + Qs staging visible

    const _Float16* QsW = Qs + wave * 1024;        // this wave's LDS region
    int cur = 0;
#pragma unroll 1
    for (int c = 0; c < 32; c++) {
        int k0 = k_lo + c * 16;
        // V fragment (h4): consumed only after the barrier -> latency hidden
        h4 v = *reinterpret_cast<const h4*>(Vb + k0 + quad * 4);

        h4 p[8];
        f4 lp = {0.f, 0.f, 0.f, 0.f};

        // ---- S phase: exp2 computed ONCE; D-layout k=quad*4+i == PV A-frag
#pragma unroll
        for (int j = 0; j < 8; j++) {
            h4 bj = (j < 4)
                ? *reinterpret_cast<const h4*>(QsW + (j * 16 + row) * 16 + quad * 4)
                : b2[j - 4];
            f4 s = __builtin_amdgcn_mfma_f32_16x16x16f16(a, bj, z4, 0, 0, 0);
            float e0 = fast_exp2(s[0]), e1 = fast_exp2(s[1]),
                  e2 = fast_exp2(s[2]), e3 = fast_exp2(s[3]);
            lp[0] += e0; lp[1] += e1; lp[2] += e2; lp[3] += e3;
            p[j] = pack4_f16(e0, e1, e2, e3);
        }

        // prefetch next chunk's K fragment (needed right after next barrier)
        int kn = (c == 31) ? k_lo : k0 + 16;
        h4 na = *reinterpret_cast<const h4*>(Kb + (kn + row) * D_ + quad * 4);

        // ---- column sums over q: 4-step butterfly over the 16 row-lanes
#pragma unroll
        for (int off = 1; off < 16; off <<= 1) {
            lp[0] += __shfl_xor(lp[0], off, 64);
            lp[1] += __shfl_xor(lp[1], off, 64);
            lp[2] += __shfl_xor(lp[2], off, 64);
            lp[3] += __shfl_xor(lp[3], off, 64);
        }
        if (row == 0) {
#pragma unroll
            for (int i = 0; i < 4; i++) atomicAdd(&l[cur][quad * 4 + i], lp[i]);
        }
        __syncthreads();

        // zero the buffer chunk c+2 will use (readers finished before this
        // barrier; its next writers are beyond the next barrier)
        int zb = cur + 2; if (zb >= 3) zb -= 3;
        if (wave == 0 && lane < 16) l[zb][lane] = 0.f;

        // ---- rl = 1/l for this lane's 4 k's, fold into V fragment
        f4 la = *reinterpret_cast<f4*>(&l[cur][quad * 4]);
        h4 rk;
        {
            union { g2 g[2]; h4 h; } u;
            u.g[0] = __builtin_amdgcn_cvt_pkrtz(fast_rcp(la[0]), fast_rcp(la[1]));
            u.g[1] = __builtin_amdgcn_cvt_pkrtz(fast_rcp(la[2]), fast_rcp(la[3]));
            rk = u.h;
        }
        h4 vs = v * rk;

        // ---- PV on retained E fragments
#pragma unroll
        for (int j = 0; j < 8; j++)
            o[j] = __builtin_amdgcn_mfma_f32_16x16x16f16(p[j], vs, o[j], 0, 0, 0);

        a = na;
        cur = cur + 1; if (cur >= 3) cur -= 3;
    }

    int n = nh >> 2, h = nh & 3;
    float* po = PO + (size_t)z * N_ * T_ * E_ + (size_t)n * T_ * E_ + h * D_ + row;
#pragma unroll
    for (int j = 0; j < 8; j++)
#pragma unroll
        for (int i = 0; i < 4; i++) {
            int q0 = (wave * 8 + j) * 16 + quad * 4 + i;
            po[(size_t)q0 * E_] = o[j][i];
        }
}

// ---------------------------------------------------------------------------
// K4: fc — out = (sum_z PO[z]) @ Wfc + bfc via 16x16x32 MFMA on Wt.
//     wave: one 16-row M-tile; 2048 tiles -> 512 blocks.
// ---------------------------------------------------------------------------
__global__ __launch_bounds__(256) void fc_kernel(
    const float* __restrict__ PO, const _Float16* __restrict__ Wt,
    const float* __restrict__ bfc, float* __restrict__ out)
{
    int tid = threadIdx.x;
    int lane = tid & 63, wave = tid >> 6;
    int row = lane & 15, quad = lane >> 4;
    int g = blockIdx.x * 4 + wave;             // M-tile id, 2048 total
    int r0 = g * 16;
    size_t base = (size_t)(r0 + row) * E_;
    const size_t zstride = (size_t)N_ * T_ * E_ / 4;   // f4 units

    h8 a[2];
#pragma unroll
    for (int half = 0; half < 2; half++) {
        f4 u0 = {0.f,0.f,0.f,0.f}, u1 = {0.f,0.f,0.f,0.f};
#pragma unroll
        for (int zz = 0; zz < 4; zz++) {
            const f4* p = reinterpret_cast<const f4*>(PO) + zz * zstride + base / 4;
            f4 w0 = p[half * 8 + quad * 2];
            f4 w1 = p[half * 8 + quad * 2 + 1];
#pragma unroll
            for (int i = 0; i < 4; i++) { u0[i] += w0[i]; u1[i] += w1[i]; }
        }
        union { h4 h[2]; h8 v; } pk;
        pk.h[0] = pack4_f16(u0[0], u0[1], u0[2], u0[3]);
        pk.h[1] = pack4_f16(u1[0], u1[1], u1[2], u1[3]);
        a[half] = pk.v;
    }
    f4 acc[4];
#pragma unroll
    for (int ne = 0; ne < 4; ne++) {
        const _Float16* wtb = Wt + (size_t)(ne * 16 + row) * 64;
        h8 b0 = *reinterpret_cast<const h8*>(wtb + quad * 8);
        h8 b1 = *reinterpret_cast<const h8*>(wtb + 32 + quad * 8);
        acc[ne] = __builtin_amdgcn_mfma_f32_16x16x32_f16(a[0], b0, (f4){0.f,0.f,0.f,0.f}, 0, 0, 0);
        acc[ne] = __builtin_amdgcn_mfma_f32_16x16x32_f16(a[1], b1, acc[ne], 0, 0, 0);
    }
#pragma unroll
    for (int ne = 0; ne < 4; ne++) {
        float bias = bfc[ne * 16 + row];
#pragma unroll
        for (int i = 0; i < 4; i++)
            out[(size_t)(r0 + quad * 4 + i) * E_ + ne * 16 + row] = acc[ne][i] + bias;
    }
}

extern "C" void kernel_launch(void* const* d_in, const int* in_sizes, int n_in,
                              void* d_out, int out_size, void* d_ws, size_t ws_size,
                              hipStream_t stream) {
    (void)in_sizes; (void)n_in; (void)out_size; (void)ws_size;
    const float* value = (const float*)d_in[0];
    const float* key   = (const float*)d_in[1];
    const float* query = (const float*)d_in[2];
    const float* Wq    = (const float*)d_in[3];
    const float* bq    = (const float*)d_in[4];
    const float* Wk    = (const float*)d_in[5];
    const float* bk    = (const float*)d_in[6];
    const float* Wv    = (const float*)d_in[7];
    const float* bv    = (const float*)d_in[8];
    const float* Wfc   = (const float*)d_in[9];
    const float* bfc   = (const float*)d_in[10];
    float* out = (float*)d_out;

    // ws bytes: Qh 0-4M | Kh 4-8M | Vt 8-12M | Wt 12M | (13-15M free) | PO 15-47M
    char* ws = (char*)d_ws;
    _Float16* Qh  = (_Float16*)(ws);
    _Float16* Kh  = (_Float16*)(ws + (4u << 20));
    _Float16* Vt  = (_Float16*)(ws + (8u << 20));
    _Float16* Wt  = (_Float16*)(ws + (12u << 20));
    float*    PO  = (float*)   (ws + (15u << 20));

    proj_kernel<<<dim3(512, 4), 256, 0, stream>>>(
        query, Wq, bq, key, Wk, bk, value, Wv, bv, Wfc, Qh, Kh, Vt, Wt);
    fused_attn_kernel<<<dim3(NH_, 4), 1024, 0, stream>>>(Qh, Kh, Vt, PO);
    fc_kernel<<<512, 256, 0, stream>>>(PO, Wt, bfc, out);
}